// Round 2
// baseline (3103.787 us; speedup 1.0000x reference)
//
#include <hip/hip_runtime.h>
#include <cstdio>

// ---------------------------------------------------------------------------
// GraphMessagePassing, f32. Round-2 restructure: one edge (node) per LANE.
//  - activations gathered per-lane into VGPRs (16B loads)
//  - weights are wave-uniform -> compiler emits s_load (scalar cache broadcast),
//    FMAs are v_fmac vdst, s_w, v_x  (zero LDS in the hot loop)
//  - h[64] accumulators lane-resident; layer2 output-stationary in 16-chunks
//  - only LDS use: per-wave 64x17 transpose tile so the atomic scatter stays
//    segment-coalesced (4 edges x 64B per atomic instr)
// ---------------------------------------------------------------------------

#define THREADS 256
#define WPB 4   // waves per block

__launch_bounds__(THREADS, 4)
__global__ void GraphMessagePassing_5952824672257_kernel(
    const float* __restrict__ nodef,   // [N,64]
    const float* __restrict__ edgef,   // [E,16]
    const int*   __restrict__ eidx,    // [2,E] int32
    const float* __restrict__ w1,      // [80,64] row-major
    const float* __restrict__ b1,      // [64]
    const float* __restrict__ w2,      // [64,64]
    const float* __restrict__ b2,      // [64]
    float* __restrict__ agg,           // [N,64] pre-zeroed
    int n_edges, int n_nodes)
{
    __shared__ float T[WPB][64][17];
    const int lane = threadIdx.x & 63;
    const int wid  = threadIdx.x >> 6;
    float (* __restrict__ Tw)[17] = T[wid];

    const long base = ((long)blockIdx.x * WPB + wid) * 64;
    const long e  = base + lane;
    const long ec = (e < n_edges) ? e : (long)n_edges - 1;

    int s = eidx[ec];
    int d = eidx[(size_t)n_edges + ec];
    if ((unsigned)s >= (unsigned)n_nodes) s = 0;
    if ((unsigned)d >= (unsigned)n_nodes) d = 0;

    const float* __restrict__ xrow = nodef + (size_t)s * 64;
    const float* __restrict__ erow = edgef + (size_t)ec * 16;

    // ---- layer 1: h[j] = b1[j] + sum_k x[k] * w1[k][j]  (k = 0..79)
    float h[64];
    #pragma unroll
    for (int j = 0; j < 64; ++j) h[j] = b1[j];      // uniform -> s_load

    float4 xc = *(const float4*)(xrow);             // k-chunk 0
    #pragma unroll 1
    for (int kb = 0; kb < 20; ++kb) {
        // prefetch next activation chunk (per-lane 16B gather)
        float4 xn = make_float4(0.f, 0.f, 0.f, 0.f);
        if (kb < 19) {
            const int i = kb + 1;
            xn = (i < 16) ? *(const float4*)(xrow + i * 4)
                          : *(const float4*)(erow + (i - 16) * 4);
        }
        const float* __restrict__ wbase = w1 + kb * 4 * 64;
        #pragma unroll
        for (int kr = 0; kr < 4; ++kr) {
            const float xk = (kr == 0) ? xc.x : (kr == 1) ? xc.y
                           : (kr == 2) ? xc.z : xc.w;
            const float* __restrict__ wr = wbase + kr * 64;  // uniform row
            #pragma unroll
            for (int j = 0; j < 64; ++j)
                h[j] = fmaf(xk, wr[j], h[j]);       // v_fmac v, s, v
        }
        xc = xn;
    }
    #pragma unroll
    for (int j = 0; j < 64; ++j) h[j] = fmaxf(h[j], 0.f);

    // dst indices for the transposed scatter: lane needs dst of edge g*4+er4
    const int oc  = lane & 15;
    const int er4 = lane >> 4;
    int dgs[16];
    #pragma unroll
    for (int g = 0; g < 16; ++g)
        dgs[g] = __shfl(d, g * 4 + er4, 64);

    // ---- layer 2 in 16-output chunks + transpose + coalesced atomic
    #pragma unroll 1
    for (int ob = 0; ob < 4; ++ob) {
        float m[16];
        #pragma unroll
        for (int c = 0; c < 16; ++c) m[c] = b2[ob * 16 + c];   // uniform
        #pragma unroll
        for (int t = 0; t < 64; ++t) {
            const float hv = h[t];
            const float* __restrict__ wr = w2 + t * 64 + ob * 16;  // uniform
            #pragma unroll
            for (int c = 0; c < 16; ++c)
                m[c] = fmaf(hv, wr[c], m[c]);
        }
        // transpose through per-wave LDS tile (stride 17: 2-way max, free)
        #pragma unroll
        for (int c = 0; c < 16; ++c) Tw[lane][c] = m[c];
        __syncthreads();
        #pragma unroll
        for (int g = 0; g < 16; ++g) {
            const int le = g * 4 + er4;
            const float v = Tw[le][oc];
            if (base + le < n_edges)
                atomicAdd(agg + (size_t)dgs[g] * 64 + ob * 16 + oc, v);
        }
        __syncthreads();
    }
}

// Node phase: same structure, D_IN = 128 ([node | agg]), plain stores.
__launch_bounds__(THREADS, 4)
__global__ void node_mlp_reg(
    const float* __restrict__ nodef,   // [N,64]
    const float* __restrict__ agg,     // [N,64]
    const float* __restrict__ w1,      // [128,64]
    const float* __restrict__ b1,      // [64]
    const float* __restrict__ w2,      // [64,64]
    const float* __restrict__ b2,      // [64]
    float* __restrict__ out,           // [N,64]
    int n_nodes)
{
    __shared__ float T[WPB][64][17];
    const int lane = threadIdx.x & 63;
    const int wid  = threadIdx.x >> 6;
    float (* __restrict__ Tw)[17] = T[wid];

    const long base = ((long)blockIdx.x * WPB + wid) * 64;
    const long n  = base + lane;
    const long nc = (n < n_nodes) ? n : (long)n_nodes - 1;

    const float* __restrict__ xrow = nodef + (size_t)nc * 64;
    const float* __restrict__ arow = agg   + (size_t)nc * 64;

    float h[64];
    #pragma unroll
    for (int j = 0; j < 64; ++j) h[j] = b1[j];

    float4 xc = *(const float4*)(xrow);
    #pragma unroll 1
    for (int kb = 0; kb < 32; ++kb) {
        float4 xn = make_float4(0.f, 0.f, 0.f, 0.f);
        if (kb < 31) {
            const int i = kb + 1;
            xn = (i < 16) ? *(const float4*)(xrow + i * 4)
                          : *(const float4*)(arow + (i - 16) * 4);
        }
        const float* __restrict__ wbase = w1 + kb * 4 * 64;
        #pragma unroll
        for (int kr = 0; kr < 4; ++kr) {
            const float xk = (kr == 0) ? xc.x : (kr == 1) ? xc.y
                           : (kr == 2) ? xc.z : xc.w;
            const float* __restrict__ wr = wbase + kr * 64;
            #pragma unroll
            for (int j = 0; j < 64; ++j)
                h[j] = fmaf(xk, wr[j], h[j]);
        }
        xc = xn;
    }
    #pragma unroll
    for (int j = 0; j < 64; ++j) h[j] = fmaxf(h[j], 0.f);

    const int oc  = lane & 15;
    const int er4 = lane >> 4;

    #pragma unroll 1
    for (int ob = 0; ob < 4; ++ob) {
        float m[16];
        #pragma unroll
        for (int c = 0; c < 16; ++c) m[c] = b2[ob * 16 + c];
        #pragma unroll
        for (int t = 0; t < 64; ++t) {
            const float hv = h[t];
            const float* __restrict__ wr = w2 + t * 64 + ob * 16;
            #pragma unroll
            for (int c = 0; c < 16; ++c)
                m[c] = fmaf(hv, wr[c], m[c]);
        }
        #pragma unroll
        for (int c = 0; c < 16; ++c) Tw[lane][c] = m[c];
        __syncthreads();
        #pragma unroll
        for (int g = 0; g < 16; ++g) {
            const int le = g * 4 + er4;
            const float v = Tw[le][oc];
            if (base + le < n_nodes)
                out[(size_t)(base + le) * 64 + ob * 16 + oc] = v;
        }
        __syncthreads();
    }
}

extern "C" void kernel_launch(void* const* d_in, const int* in_sizes, int n_in,
                              void* d_out, int out_size, void* d_ws, size_t ws_size,
                              hipStream_t stream) {
    // setup_inputs() order:
    // 0 node_features[N,64] f32, 1 edge_features[E,16] f32, 2 edge_index[2,E] i32,
    // 3 w_m1[80,64], 4 b_m1, 5 w_m2[64,64], 6 b_m2,
    // 7 w_u1[128,64], 8 b_u1, 9 w_u2[64,64], 10 b_u2   (all f32)
    const float* nodef = (const float*)d_in[0];
    const float* edgef = (const float*)d_in[1];
    const int*   eidx  = (const int*)d_in[2];
    const float* w_m1  = (const float*)d_in[3];
    const float* b_m1  = (const float*)d_in[4];
    const float* w_m2  = (const float*)d_in[5];
    const float* b_m2  = (const float*)d_in[6];
    const float* w_u1  = (const float*)d_in[7];
    const float* b_u1  = (const float*)d_in[8];
    const float* w_u2  = (const float*)d_in[9];
    const float* b_u2  = (const float*)d_in[10];
    float* out = (float*)d_out;

    const int n_nodes = out_size / 64;
    const int n_edges = in_sizes[2] / 2;

    fprintf(stderr, "[KL] f32 lane-per-edge pipeline E=%d N=%d ws=%zu\n",
            n_edges, n_nodes, ws_size);
    fflush(stderr);

    // agg[N,64] f32 in workspace (12.8 MB; ws is 320 MB)
    float* agg = (float*)d_ws;
    hipMemsetAsync(agg, 0, (size_t)n_nodes * 64 * sizeof(float), stream);

    const int blocks_e = (n_edges + THREADS - 1) / THREADS;   // 64 edges/wave
    GraphMessagePassing_5952824672257_kernel<<<blocks_e, THREADS, 0, stream>>>(
        nodef, edgef, eidx, w_m1, b_m1, w_m2, b_m2, agg, n_edges, n_nodes);

    const int blocks_n = (n_nodes + THREADS - 1) / THREADS;
    node_mlp_reg<<<blocks_n, THREADS, 0, stream>>>(
        nodef, agg, w_u1, b_u1, w_u2, b_u2, out, n_nodes);

    hipError_t le = hipGetLastError();
    fprintf(stderr, "[KL] last=%d(%s)\n", (int)le, hipGetErrorName(le));
    fflush(stderr);
}